// Round 3
// baseline (988.522 us; speedup 1.0000x reference)
//
#include <hip/hip_runtime.h>
#include <hip/hip_fp16.h>

// MoE top-2 SwiGLU, MI355X. Sparse grouped-GEMM, 256-aligned expert segments.
// GEMMs: 8-wave 512-thread, 32x32x16 f16 MFMA, BK=32, 4 LDS buffers,
// distance-3 prefetch (global_load_lds w16), ONE barrier + counted vmcnt per
// K-step, XOR-swizzled LDS via pre-swizzled global source, setprio on MFMA,
// XCD-chunked bijective block swizzle.
// gemm1: virtual-N=8192, w1/w3 interleaved at 32-col granularity -> silu*mul -> h fp16.
// gemm2: h @ w2^T -> y fp32. combine: out = g0*y0 + g1*y1.

#define NTOK 8192
#define D_ 1024
#define F_ 4096
#define E_ 8
#define SLOT_CAP 18432  // 2*8192 + 8*256

using half8 = __attribute__((ext_vector_type(8))) _Float16;
using half4 = __attribute__((ext_vector_type(4))) _Float16;
using f32x16 = __attribute__((ext_vector_type(16))) float;

__device__ __forceinline__ void gload16(const void* g, void* l) {
  __builtin_amdgcn_global_load_lds((const __attribute__((address_space(1))) void*)g,
                                   (__attribute__((address_space(3))) void*)l, 16, 0, 0);
}

// ---------------- fp32 -> fp16 convert ----------------
__global__ __launch_bounds__(256) void cvt_kernel(const float* __restrict__ src,
                                                  _Float16* __restrict__ dst, int n4) {
  int i = blockIdx.x * 256 + threadIdx.x;
  int stride = gridDim.x * 256;
  for (; i < n4; i += stride) {
    float4 v = ((const float4*)src)[i];
    half4 h;
    h.x = (_Float16)v.x; h.y = (_Float16)v.y; h.z = (_Float16)v.z; h.w = (_Float16)v.w;
    ((half4*)dst)[i] = h;
  }
}

// w1,w3 -> interleaved virtual rows w13[e][8192][1024]:
// vrow = ((f>>5)<<6) | (sel<<5) | (f&31); sel 0=w1(gate), 1=w3(up).
// A 32-virtual-col MFMA frag is then pure-gate or pure-up over 32 consecutive f.
__global__ __launch_bounds__(256) void cvt_w13_kernel(const float* __restrict__ w1,
                                                      const float* __restrict__ w3,
                                                      _Float16* __restrict__ w13, int n4) {
  int i = blockIdx.x * 256 + threadIdx.x;
  int stride = gridDim.x * 256;
  for (; i < n4; i += stride) {
    int d4 = i & 255;   // D/4 = 256
    int row = i >> 8;   // e*4096 + f
    int e = row >> 12, f = row & 4095;
    size_t vbase = ((size_t)e << 13) | ((size_t)(f >> 5) << 6) | (size_t)(f & 31);
    float4 v1 = ((const float4*)w1)[i];
    float4 v3 = ((const float4*)w3)[i];
    half4 h1, h3;
    h1.x = (_Float16)v1.x; h1.y = (_Float16)v1.y; h1.z = (_Float16)v1.z; h1.w = (_Float16)v1.w;
    h3.x = (_Float16)v3.x; h3.y = (_Float16)v3.y; h3.z = (_Float16)v3.z; h3.w = (_Float16)v3.w;
    ((half4*)w13)[vbase * 256 + d4] = h1;
    ((half4*)w13)[(vbase + 32) * 256 + d4] = h3;
  }
}

// ---------------- router (+ fused x fp32->fp16) ----------------
__global__ __launch_bounds__(256) void router_kernel(
    const float* __restrict__ x, const float* __restrict__ rw, const float* __restrict__ rbias,
    _Float16* __restrict__ x16, int* __restrict__ tok_e, float* __restrict__ tok_g,
    int* __restrict__ counts) {
  int wv = threadIdx.x >> 6, lane = threadIdx.x & 63;
  int t = blockIdx.x * 4 + wv;
  const float4* xr = (const float4*)(x + (size_t)t * D_);
  float acc[E_];
#pragma unroll
  for (int e = 0; e < E_; ++e) acc[e] = 0.f;
  for (int i = lane; i < D_ / 4; i += 64) {
    float4 xv = xr[i];
    half4 hx;
    hx.x = (_Float16)xv.x; hx.y = (_Float16)xv.y; hx.z = (_Float16)xv.z; hx.w = (_Float16)xv.w;
    ((half4*)(x16 + (size_t)t * D_))[i] = hx;
#pragma unroll
    for (int e = 0; e < E_; ++e) {
      float4 wv4 = ((const float4*)(rw + (size_t)e * D_))[i];
      acc[e] += xv.x * wv4.x + xv.y * wv4.y + xv.z * wv4.z + xv.w * wv4.w;
    }
  }
#pragma unroll
  for (int e = 0; e < E_; ++e) {
#pragma unroll
    for (int off = 32; off > 0; off >>= 1) acc[e] += __shfl_down(acc[e], off);
  }
  if (lane == 0) {
    float p[E_], mx = -1e30f;
#pragma unroll
    for (int e = 0; e < E_; ++e) { p[e] = acc[e] + rbias[e]; mx = fmaxf(mx, p[e]); }
#pragma unroll
    for (int e = 0; e < E_; ++e) p[e] = expf(p[e] - mx);
    int i0 = 0;
#pragma unroll
    for (int e = 1; e < E_; ++e) if (p[e] > p[i0]) i0 = e;
    int i1 = (i0 == 0) ? 1 : 0;
#pragma unroll
    for (int e = 0; e < E_; ++e) if (e != i0 && p[e] > p[i1]) i1 = e;
    float s = p[i0] + p[i1];
    tok_e[t * 2] = i0; tok_e[t * 2 + 1] = i1;
    tok_g[t * 2] = p[i0] / s; tok_g[t * 2 + 1] = p[i1] / s;
    atomicAdd(&counts[i0], 1); atomicAdd(&counts[i1], 1);
  }
}

__global__ void init_kernel(int* slot_token, int* counts, int* cursor) {
  int i = blockIdx.x * 256 + threadIdx.x;
  if (blockIdx.x == 0 && threadIdx.x < E_) { counts[threadIdx.x] = 0; cursor[threadIdx.x] = 0; }
  if (i < SLOT_CAP) slot_token[i] = 0;  // padding -> token 0 (never combined)
}

__global__ void scan_kernel(const int* __restrict__ counts, int* __restrict__ offs) {
  if (threadIdx.x == 0) {
    int o = 0;
    for (int e = 0; e < E_; ++e) { offs[e] = o; o += ((counts[e] + 255) / 256) * 256; }
    offs[E_] = o;
  }
}

__global__ void scatter_kernel(const int* __restrict__ tok_e, const int* __restrict__ offs,
                               int* __restrict__ cursor, int* __restrict__ slot_token,
                               int* __restrict__ slot_of) {
  int i = blockIdx.x * 256 + threadIdx.x;
  if (i >= NTOK * 2) return;
  int e = tok_e[i];
  int pos = offs[e] + atomicAdd(&cursor[e], 1);
  slot_token[pos] = i >> 1;
  slot_of[i] = pos;
}

// ---------------- pipelined grouped GEMM (32x32x16 f16) ----------------
// BM in {128,256}, BN=256 fixed, 8 waves (2 wr x 4 wc), per-wave (BM/2) x 64.
// MODE 0: gather-A rows via slot_token, swiglu epilogue -> fp16 h.
// MODE 1: direct-A, fp32 out.
template <int BM, int MODE, int KD, int NBN, int RPX, int BEROWS>
__global__ __launch_bounds__(512, 1) void moe_gemm_kernel(
    const _Float16* __restrict__ Amat, const _Float16* __restrict__ Bmat,
    const int* __restrict__ slot_token, const int* __restrict__ offs,
    void* __restrict__ outp) {
  constexpr int MROW = BM / 64;        // m-frags per wave
  constexpr int AINS = BM / 128;       // A stage instrs (512 thr x 16B = 128 rows)
  constexpr int S = AINS + 2;          // stage instrs per tile
  constexpr int AH = BM * 32;          // A halves per buffer
  constexpr int BUFH = (BM + 256) * 32;
  constexpr int NT = KD / 32;
  __shared__ _Float16 lds[4 * BUFH];

  // bijective XCD-chunked swizzle; 8-rb bands, rb-fastest (B-panel L2 sharing)
  int id = blockIdx.x;
  int xcd = id & 7, idx = id >> 3;  // grid = 8 * RPX * NBN
  int band = idx / (8 * NBN);
  int i2 = idx - band * (8 * NBN);
  int rib = (RPX - band * 8) < 8 ? (RPX - band * 8) : 8;
  int nb = i2 / rib;
  int rloc = band * 8 + (i2 - nb * rib);
  int rb = xcd * RPX + rloc;
  int row0 = rb * BM;
  if (row0 >= offs[E_]) return;
  int e = 0;
#pragma unroll
  for (int i = 1; i < E_; ++i) if (row0 >= offs[i]) e = i;

  int t = threadIdx.x, l = t & 63, w = t >> 6;
  int wr = w >> 2, wc = w & 3;
  int lr = l & 31, hi = l >> 5;
  int srow = t >> 2;                           // 0..127 staging row
  int gsrc8 = ((t & 3) ^ ((t >> 3) & 3)) * 8;  // pre-swizzled source k-granule

  const _Float16* aSrc[AINS];
  if constexpr (MODE == 0) {
#pragma unroll
    for (int ins = 0; ins < AINS; ++ins) {
      int tk = slot_token[row0 + srow + ins * 128];
      aSrc[ins] = Amat + (size_t)tk * KD + gsrc8;
    }
  } else {
#pragma unroll
    for (int ins = 0; ins < AINS; ++ins)
      aSrc[ins] = Amat + (size_t)(row0 + srow + ins * 128) * KD + gsrc8;
  }
  const _Float16* bSrc0 = Bmat + ((size_t)e * BEROWS + (size_t)nb * 256 + srow) * KD + gsrc8;
  const _Float16* bSrc1 = bSrc0 + (size_t)128 * KD;

  auto stage = [&](int bi, int tt) {
#pragma unroll
    for (int ins = 0; ins < AINS; ++ins)
      gload16(aSrc[ins] + tt * 32, &lds[bi * BUFH + w * 512 + ins * 4096]);
    gload16(bSrc0 + tt * 32, &lds[bi * BUFH + AH + w * 512]);
    gload16(bSrc1 + tt * 32, &lds[bi * BUFH + AH + w * 512 + 4096]);
  };

  // swizzled read offsets (halves): slot = row*4 + (g ^ ((row>>1)&3)), g = kk*2+hi
  int offA[MROW][2], offB[2][2];
#pragma unroll
  for (int mi = 0; mi < MROW; ++mi)
#pragma unroll
    for (int kk = 0; kk < 2; ++kk) {
      int r = wr * (BM / 2) + mi * 32 + lr;
      offA[mi][kk] = (r * 4 + ((kk * 2 + hi) ^ ((r >> 1) & 3))) * 8;
    }
#pragma unroll
  for (int ni = 0; ni < 2; ++ni)
#pragma unroll
    for (int kk = 0; kk < 2; ++kk) {
      int r = wc * 64 + ni * 32 + lr;
      offB[ni][kk] = AH + (r * 4 + ((kk * 2 + hi) ^ ((r >> 1) & 3))) * 8;
    }

  f32x16 acc[MROW][2];
#pragma unroll
  for (int m = 0; m < MROW; ++m)
#pragma unroll
    for (int n = 0; n < 2; ++n)
#pragma unroll
      for (int i = 0; i < 16; ++i) acc[m][n][i] = 0.f;

  // prologue: stage tiles 0..2, wait tile 0 (2 tiles stay in flight)
  stage(0, 0); stage(1, 1); stage(2, 2);
  asm volatile("s_waitcnt vmcnt(%0)" ::"i"(2 * S) : "memory");
  __builtin_amdgcn_s_barrier();
  __builtin_amdgcn_sched_barrier(0);

  for (int j = 0; j < NT; ++j) {
    int bi = j & 3, bs = (j + 3) & 3;
    const _Float16* base = lds + bi * BUFH;
    half8 a[MROW][2], b[2][2];
#pragma unroll
    for (int mi = 0; mi < MROW; ++mi)
#pragma unroll
      for (int kk = 0; kk < 2; ++kk) a[mi][kk] = *(const half8*)(base + offA[mi][kk]);
#pragma unroll
    for (int ni = 0; ni < 2; ++ni)
#pragma unroll
      for (int kk = 0; kk < 2; ++kk) b[ni][kk] = *(const half8*)(base + offB[ni][kk]);
    if (j + 3 < NT) stage(bs, j + 3);
    __builtin_amdgcn_s_setprio(1);
#pragma unroll
    for (int kk = 0; kk < 2; ++kk)
#pragma unroll
      for (int mi = 0; mi < MROW; ++mi)
#pragma unroll
        for (int ni = 0; ni < 2; ++ni)
          acc[mi][ni] =
              __builtin_amdgcn_mfma_f32_32x32x16_f16(a[mi][kk], b[ni][kk], acc[mi][ni], 0, 0, 0);
    __builtin_amdgcn_s_setprio(0);
    // boundary: ensure tile j+1 resident on all waves; keep rest in flight
    int ahead = NT - 1 - j;
    if (ahead >= 3)      asm volatile("s_waitcnt vmcnt(%0)" ::"i"(2 * S) : "memory");
    else if (ahead == 2) asm volatile("s_waitcnt vmcnt(%0)" ::"i"(S) : "memory");
    else if (ahead == 1) asm volatile("s_waitcnt vmcnt(0)" ::: "memory");
    if (ahead >= 1) {
      __builtin_amdgcn_s_barrier();
      __builtin_amdgcn_sched_barrier(0);
    }
  }

  // epilogue. C/D: col = lane&31, row = (i&3) + 8*(i>>2) + 4*(lane>>5)
  if constexpr (MODE == 0) {
    _Float16* hb = (_Float16*)outp;
    int fc = (nb * 4 + wc) * 32 + lr;
#pragma unroll
    for (int mi = 0; mi < MROW; ++mi) {
      int rb0 = row0 + wr * (BM / 2) + mi * 32 + 4 * hi;
#pragma unroll
      for (int i = 0; i < 16; ++i) {
        int rr = rb0 + (i & 3) + 8 * (i >> 2);
        float gv = acc[mi][0][i];
        float hv = gv / (1.f + __expf(-gv)) * acc[mi][1][i];
        hb[(size_t)rr * F_ + fc] = (_Float16)hv;
      }
    }
  } else {
    float* yb = (float*)outp;
#pragma unroll
    for (int mi = 0; mi < MROW; ++mi) {
      int rb0 = row0 + wr * (BM / 2) + mi * 32 + 4 * hi;
#pragma unroll
      for (int ni = 0; ni < 2; ++ni) {
        int col = nb * 256 + wc * 64 + ni * 32 + lr;
#pragma unroll
        for (int i = 0; i < 16; ++i) {
          int rr = rb0 + (i & 3) + 8 * (i >> 2);
          yb[(size_t)rr * D_ + col] = acc[mi][ni][i];
        }
      }
    }
  }
}

// ---------------- combine ----------------
__global__ __launch_bounds__(256) void combine_kernel(
    const float* __restrict__ ybuf, const int* __restrict__ slot_of,
    const float* __restrict__ tok_g, float* __restrict__ out) {
  int t = blockIdx.x, i = threadIdx.x;
  int s0 = slot_of[t * 2], s1 = slot_of[t * 2 + 1];
  float g0 = tok_g[t * 2], g1 = tok_g[t * 2 + 1];
  float4 a = ((const float4*)(ybuf + (size_t)s0 * D_))[i];
  float4 b = ((const float4*)(ybuf + (size_t)s1 * D_))[i];
  float4 r;
  r.x = g0 * a.x + g1 * b.x;
  r.y = g0 * a.y + g1 * b.y;
  r.z = g0 * a.z + g1 * b.z;
  r.w = g0 * a.w + g1 * b.w;
  ((float4*)(out + (size_t)t * D_))[i] = r;
}

extern "C" void kernel_launch(void* const* d_in, const int* in_sizes, int n_in,
                              void* d_out, int out_size, void* d_ws, size_t ws_size,
                              hipStream_t stream) {
  const float* x  = (const float*)d_in[0];
  const float* rw = (const float*)d_in[1];
  const float* rbc = (const float*)d_in[2];
  const float* w1 = (const float*)d_in[3];
  const float* w2 = (const float*)d_in[4];  // dict order: w2 before w3
  const float* w3 = (const float*)d_in[5];
  float* out = (float*)d_out;

  char* ws = (char*)d_ws;
  size_t off = 0;
  auto take = [&](size_t bytes) {
    char* p = ws + off;
    off = (off + bytes + 255) & ~(size_t)255;
    return p;
  };
  _Float16* x16 = (_Float16*)take((size_t)NTOK * D_ * 2);
  _Float16* w13 = (_Float16*)take((size_t)E_ * 2 * F_ * D_ * 2);  // 128 MB
  _Float16* w2h = (_Float16*)take((size_t)E_ * D_ * F_ * 2);      // 64 MB
  _Float16* hbuf = (_Float16*)take((size_t)SLOT_CAP * F_ * 2);    // 151 MB
  float* ybuf = (float*)take((size_t)SLOT_CAP * D_ * 4);          // 75.5 MB
  int* slot_token = (int*)take((size_t)SLOT_CAP * 4);
  int* tok_e = (int*)take((size_t)NTOK * 2 * 4);
  float* tok_g = (float*)take((size_t)NTOK * 2 * 4);
  int* slot_of = (int*)take((size_t)NTOK * 2 * 4);
  int* counts = (int*)take(E_ * 4);
  int* cursor = (int*)take(E_ * 4);
  int* offs = (int*)take((E_ + 1) * 4);

  cvt_w13_kernel<<<4096, 256, 0, stream>>>(w1, w3, w13, E_ * F_ * D_ / 4);
  cvt_kernel<<<4096, 256, 0, stream>>>(w2, w2h, E_ * D_ * F_ / 4);
  init_kernel<<<(SLOT_CAP + 255) / 256, 256, 0, stream>>>(slot_token, counts, cursor);
  router_kernel<<<NTOK / 4, 256, 0, stream>>>(x, rw, rbc, x16, tok_e, tok_g, counts);
  scan_kernel<<<1, 64, 0, stream>>>(counts, offs);
  scatter_kernel<<<(NTOK * 2 + 255) / 256, 256, 0, stream>>>(tok_e, offs, cursor, slot_token, slot_of);
  // gemm1: M<=18432 x Nvirt=8192 x K=1024, BM=256 -> grid 8*9*32
  moe_gemm_kernel<256, 0, 1024, 32, 9, 8192><<<2304, 512, 0, stream>>>(
      x16, w13, slot_token, offs, (void*)hbuf);
  // gemm2: M<=18432 x N=1024 x K=4096, BM=128 -> grid 8*18*4
  moe_gemm_kernel<128, 1, 4096, 4, 18, 1024><<<576, 512, 0, stream>>>(
      hbuf, w2h, slot_token, offs, (void*)ybuf);
  combine_kernel<<<NTOK, 256, 0, stream>>>(ybuf, slot_of, tok_g, out);
}

// Round 4
// 910.093 us; speedup vs baseline: 1.0862x; 1.0862x over previous
//
#include <hip/hip_runtime.h>
#include <hip/hip_fp16.h>

// MoE top-2 SwiGLU, MI355X. Sparse grouped-GEMM, 256-aligned expert segments.
// Both GEMMs: 8-wave 512-thread, 16x16x32 f16 MFMA (round-2 proven 0-conflict
// LDS pattern), BM=128/BN=256/BK=32, 3 LDS buffers (72 KB -> 2 blocks/CU),
// distance-2 prefetch via global_load_lds w16, one barrier + counted vmcnt per
// K-step, XOR-swizzled LDS via pre-swizzled global source, setprio on MFMA,
// XCD-chunked bijective block swizzle.
// gemm1: virtual-N=8192 (w1/w3 interleaved at 16-col granularity) -> silu*mul -> h fp16.
// gemm2: h @ w2^T -> y fp32. combine: out = g0*y0 + g1*y1.

#define NTOK 8192
#define D_ 1024
#define F_ 4096
#define E_ 8
#define SLOT_CAP 18432  // 2*8192 + 8*256

using half8 = __attribute__((ext_vector_type(8))) _Float16;
using half4 = __attribute__((ext_vector_type(4))) _Float16;
using f32x4 = __attribute__((ext_vector_type(4))) float;

__device__ __forceinline__ void gload16(const void* g, void* l) {
  __builtin_amdgcn_global_load_lds((const __attribute__((address_space(1))) void*)g,
                                   (__attribute__((address_space(3))) void*)l, 16, 0, 0);
}

// ---------------- fp32 -> fp16 convert ----------------
__global__ __launch_bounds__(256) void cvt_kernel(const float* __restrict__ src,
                                                  _Float16* __restrict__ dst, int n4) {
  int i = blockIdx.x * 256 + threadIdx.x;
  int stride = gridDim.x * 256;
  for (; i < n4; i += stride) {
    float4 v = ((const float4*)src)[i];
    half4 h;
    h.x = (_Float16)v.x; h.y = (_Float16)v.y; h.z = (_Float16)v.z; h.w = (_Float16)v.w;
    ((half4*)dst)[i] = h;
  }
}

// w1,w3 -> interleaved virtual rows w13[e][8192][1024]:
// vrow = ((f>>4)<<5) | (sel<<4) | (f&15); sel 0=w1(gate), 1=w3(up).
__global__ __launch_bounds__(256) void cvt_w13_kernel(const float* __restrict__ w1,
                                                      const float* __restrict__ w3,
                                                      _Float16* __restrict__ w13, int n4) {
  int i = blockIdx.x * 256 + threadIdx.x;
  int stride = gridDim.x * 256;
  for (; i < n4; i += stride) {
    int d4 = i & 255;   // D/4 = 256
    int row = i >> 8;   // e*4096 + f
    int e = row >> 12, f = row & 4095;
    size_t vbase = ((size_t)e << 13) | ((size_t)(f >> 4) << 5) | (size_t)(f & 15);
    float4 v1 = ((const float4*)w1)[i];
    float4 v3 = ((const float4*)w3)[i];
    half4 h1, h3;
    h1.x = (_Float16)v1.x; h1.y = (_Float16)v1.y; h1.z = (_Float16)v1.z; h1.w = (_Float16)v1.w;
    h3.x = (_Float16)v3.x; h3.y = (_Float16)v3.y; h3.z = (_Float16)v3.z; h3.w = (_Float16)v3.w;
    ((half4*)w13)[vbase * 256 + d4] = h1;
    ((half4*)w13)[(vbase + 16) * 256 + d4] = h3;
  }
}

// ---------------- router (+ fused x fp32->fp16) ----------------
__global__ __launch_bounds__(256) void router_kernel(
    const float* __restrict__ x, const float* __restrict__ rw, const float* __restrict__ rbias,
    _Float16* __restrict__ x16, int* __restrict__ tok_e, float* __restrict__ tok_g,
    int* __restrict__ counts) {
  int wv = threadIdx.x >> 6, lane = threadIdx.x & 63;
  int t = blockIdx.x * 4 + wv;
  const float4* xr = (const float4*)(x + (size_t)t * D_);
  float acc[E_];
#pragma unroll
  for (int e = 0; e < E_; ++e) acc[e] = 0.f;
  for (int i = lane; i < D_ / 4; i += 64) {
    float4 xv = xr[i];
    half4 hx;
    hx.x = (_Float16)xv.x; hx.y = (_Float16)xv.y; hx.z = (_Float16)xv.z; hx.w = (_Float16)xv.w;
    ((half4*)(x16 + (size_t)t * D_))[i] = hx;
#pragma unroll
    for (int e = 0; e < E_; ++e) {
      float4 wv4 = ((const float4*)(rw + (size_t)e * D_))[i];
      acc[e] += xv.x * wv4.x + xv.y * wv4.y + xv.z * wv4.z + xv.w * wv4.w;
    }
  }
#pragma unroll
  for (int e = 0; e < E_; ++e) {
#pragma unroll
    for (int off = 32; off > 0; off >>= 1) acc[e] += __shfl_down(acc[e], off);
  }
  if (lane == 0) {
    float p[E_], mx = -1e30f;
#pragma unroll
    for (int e = 0; e < E_; ++e) { p[e] = acc[e] + rbias[e]; mx = fmaxf(mx, p[e]); }
#pragma unroll
    for (int e = 0; e < E_; ++e) p[e] = expf(p[e] - mx);
    int i0 = 0;
#pragma unroll
    for (int e = 1; e < E_; ++e) if (p[e] > p[i0]) i0 = e;
    int i1 = (i0 == 0) ? 1 : 0;
#pragma unroll
    for (int e = 0; e < E_; ++e) if (e != i0 && p[e] > p[i1]) i1 = e;
    float s = p[i0] + p[i1];
    tok_e[t * 2] = i0; tok_e[t * 2 + 1] = i1;
    tok_g[t * 2] = p[i0] / s; tok_g[t * 2 + 1] = p[i1] / s;
    atomicAdd(&counts[i0], 1); atomicAdd(&counts[i1], 1);
  }
}

__global__ void init_kernel(int* slot_token, int* counts, int* cursor) {
  int i = blockIdx.x * 256 + threadIdx.x;
  if (blockIdx.x == 0 && threadIdx.x < E_) { counts[threadIdx.x] = 0; cursor[threadIdx.x] = 0; }
  if (i < SLOT_CAP) slot_token[i] = 0;  // padding -> token 0 (never combined)
}

__global__ void scan_kernel(const int* __restrict__ counts, int* __restrict__ offs) {
  if (threadIdx.x == 0) {
    int o = 0;
    for (int e = 0; e < E_; ++e) { offs[e] = o; o += ((counts[e] + 255) / 256) * 256; }
    offs[E_] = o;
  }
}

__global__ void scatter_kernel(const int* __restrict__ tok_e, const int* __restrict__ offs,
                               int* __restrict__ cursor, int* __restrict__ slot_token,
                               int* __restrict__ slot_of) {
  int i = blockIdx.x * 256 + threadIdx.x;
  if (i >= NTOK * 2) return;
  int e = tok_e[i];
  int pos = offs[e] + atomicAdd(&cursor[e], 1);
  slot_token[pos] = i >> 1;
  slot_of[i] = pos;
}

// ---------------- pipelined grouped GEMM (16x16x32 f16, BM=128, BN=256) ----------------
// 8 waves (2 wr x 4 wc), per-wave 64 x 64 output. 3 LDS buffers, distance-2 prefetch.
// MODE 0: gather-A rows via slot_token, swiglu epilogue -> fp16 h.  MODE 1: direct-A -> fp32.
template <int MODE, int KD, int NBN, int RPX, int BEROWS>
__global__ __launch_bounds__(512, 4) void moe_gemm_kernel(
    const _Float16* __restrict__ Amat, const _Float16* __restrict__ Bmat,
    const int* __restrict__ slot_token, const int* __restrict__ offs,
    void* __restrict__ outp) {
  constexpr int BM = 128;
  constexpr int BUFH = (BM + 256) * 32;  // 12288 halves = 24 KB
  constexpr int NT = KD / 32;
  __shared__ _Float16 lds[3 * BUFH];

  // bijective XCD-chunked swizzle; 8-rb bands, rb-fastest (B-panel L2 sharing)
  int id = blockIdx.x;
  int xcd = id & 7, idx = id >> 3;  // grid = 8 * RPX * NBN
  int band = idx / (8 * NBN);
  int i2 = idx - band * (8 * NBN);
  int rib = (RPX - band * 8) < 8 ? (RPX - band * 8) : 8;
  int nb = i2 / rib;
  int rloc = band * 8 + (i2 - nb * rib);
  int rb = xcd * RPX + rloc;
  int row0 = rb * BM;
  if (row0 >= offs[E_]) return;
  int e = 0;
#pragma unroll
  for (int i = 1; i < E_; ++i) if (row0 >= offs[i]) e = i;

  int t = threadIdx.x, l = t & 63, w = t >> 6;
  int wr = w >> 2, wc = w & 3;
  int srow = t >> 2;                           // 0..127 staging row
  int gsrc8 = ((l & 3) ^ ((l >> 3) & 3)) * 8;  // pre-swizzled source k-granule

  const _Float16* aSrc;
  if constexpr (MODE == 0) {
    int tk = slot_token[row0 + srow];
    aSrc = Amat + (size_t)tk * KD + gsrc8;
  } else {
    aSrc = Amat + (size_t)(row0 + srow) * KD + gsrc8;
  }
  const _Float16* bSrc0 = Bmat + ((size_t)e * BEROWS + (size_t)nb * 256 + srow) * KD + gsrc8;
  const _Float16* bSrc1 = bSrc0 + (size_t)128 * KD;

  auto stage = [&](int bi, int tt) {
    gload16(aSrc + tt * 32, &lds[bi * BUFH + w * 512]);
    gload16(bSrc0 + tt * 32, &lds[bi * BUFH + 4096 + w * 512]);
    gload16(bSrc1 + tt * 32, &lds[bi * BUFH + 4096 + w * 512 + 4096]);
  };

  // round-2 proven read pattern: 16-row frags, granule kg = l>>4
  int fr = l & 15, kg = l >> 4;
  int swz8 = (kg ^ ((fr >> 1) & 3)) * 8;
  const int rA = (wr * 64 + fr) * 32 + swz8;
  const int rB = 4096 + (wc * 64 + fr) * 32 + swz8;
  auto ldA = [&](int bi, int mi) { return *(const half8*)&lds[bi * BUFH + rA + mi * 512]; };
  auto ldB = [&](int bi, int ni) { return *(const half8*)&lds[bi * BUFH + rB + ni * 512]; };

  f32x4 acc[4][4];
#pragma unroll
  for (int m = 0; m < 4; ++m)
#pragma unroll
    for (int n = 0; n < 4; ++n) acc[m][n] = (f32x4){0.f, 0.f, 0.f, 0.f};

  // prologue: stage tiles 0,1; wait tile 0 (tile 1's 3 loads stay in flight)
  stage(0, 0); stage(1, 1);
  asm volatile("s_waitcnt vmcnt(3)" ::: "memory");
  __builtin_amdgcn_s_barrier();
  __builtin_amdgcn_sched_barrier(0);

  int b0 = 0, b1 = 1, b2 = 2;
  for (int j = 0; j < NT; ++j) {
    half8 a[4], b[4];
#pragma unroll
    for (int mi = 0; mi < 4; ++mi) a[mi] = ldA(b0, mi);
#pragma unroll
    for (int ni = 0; ni < 4; ++ni) b[ni] = ldB(b0, ni);
    if (j + 2 < NT) stage(b2, j + 2);
    __builtin_amdgcn_s_setprio(1);
#pragma unroll
    for (int mi = 0; mi < 4; ++mi)
#pragma unroll
      for (int ni = 0; ni < 4; ++ni)
        acc[mi][ni] = __builtin_amdgcn_mfma_f32_16x16x32_f16(a[mi], b[ni], acc[mi][ni], 0, 0, 0);
    __builtin_amdgcn_s_setprio(0);
    int ahead = NT - 1 - j;
    if (ahead >= 2)      asm volatile("s_waitcnt vmcnt(3)" ::: "memory");
    else if (ahead == 1) asm volatile("s_waitcnt vmcnt(0)" ::: "memory");
    if (ahead >= 1) {
      __builtin_amdgcn_s_barrier();
      __builtin_amdgcn_sched_barrier(0);
    }
    int tmp = b0; b0 = b1; b1 = b2; b2 = tmp;
  }

  // epilogue. C/D 16x16: col = lane&15, row = (lane>>4)*4 + i  [m89 verified]
  int q4 = kg * 4;
  if constexpr (MODE == 0) {
    _Float16* hb = (_Float16*)outp;
#pragma unroll
    for (int mi = 0; mi < 4; ++mi) {
      size_t rbase = (size_t)(row0 + wr * 64 + mi * 16 + q4);
#pragma unroll
      for (int p = 0; p < 2; ++p) {
        int fc = nb * 128 + (wc * 2 + p) * 16 + fr;
#pragma unroll
        for (int i = 0; i < 4; ++i) {
          float gv = acc[mi][2 * p][i];
          float hv = gv / (1.f + __expf(-gv)) * acc[mi][2 * p + 1][i];
          hb[(rbase + i) * (size_t)F_ + fc] = (_Float16)hv;
        }
      }
    }
  } else {
    float* yb = (float*)outp;
#pragma unroll
    for (int mi = 0; mi < 4; ++mi) {
      size_t rbase = (size_t)(row0 + wr * 64 + mi * 16 + q4);
#pragma unroll
      for (int ni = 0; ni < 4; ++ni) {
        int col = nb * 256 + wc * 64 + ni * 16 + fr;
#pragma unroll
        for (int i = 0; i < 4; ++i)
          yb[(rbase + i) * (size_t)D_ + col] = acc[mi][ni][i];
      }
    }
  }
}

// ---------------- combine ----------------
__global__ __launch_bounds__(256) void combine_kernel(
    const float* __restrict__ ybuf, const int* __restrict__ slot_of,
    const float* __restrict__ tok_g, float* __restrict__ out) {
  int t = blockIdx.x, i = threadIdx.x;
  int s0 = slot_of[t * 2], s1 = slot_of[t * 2 + 1];
  float g0 = tok_g[t * 2], g1 = tok_g[t * 2 + 1];
  float4 a = ((const float4*)(ybuf + (size_t)s0 * D_))[i];
  float4 b = ((const float4*)(ybuf + (size_t)s1 * D_))[i];
  float4 r;
  r.x = g0 * a.x + g1 * b.x;
  r.y = g0 * a.y + g1 * b.y;
  r.z = g0 * a.z + g1 * b.z;
  r.w = g0 * a.w + g1 * b.w;
  ((float4*)(out + (size_t)t * D_))[i] = r;
}

extern "C" void kernel_launch(void* const* d_in, const int* in_sizes, int n_in,
                              void* d_out, int out_size, void* d_ws, size_t ws_size,
                              hipStream_t stream) {
  const float* x  = (const float*)d_in[0];
  const float* rw = (const float*)d_in[1];
  const float* rbc = (const float*)d_in[2];
  const float* w1 = (const float*)d_in[3];
  const float* w2 = (const float*)d_in[4];  // dict order: w2 before w3
  const float* w3 = (const float*)d_in[5];
  float* out = (float*)d_out;

  char* ws = (char*)d_ws;
  size_t off = 0;
  auto take = [&](size_t bytes) {
    char* p = ws + off;
    off = (off + bytes + 255) & ~(size_t)255;
    return p;
  };
  _Float16* x16 = (_Float16*)take((size_t)NTOK * D_ * 2);
  _Float16* w13 = (_Float16*)take((size_t)E_ * 2 * F_ * D_ * 2);  // 128 MB
  _Float16* w2h = (_Float16*)take((size_t)E_ * D_ * F_ * 2);      // 64 MB
  _Float16* hbuf = (_Float16*)take((size_t)SLOT_CAP * F_ * 2);    // 151 MB
  float* ybuf = (float*)take((size_t)SLOT_CAP * D_ * 4);          // 75.5 MB
  int* slot_token = (int*)take((size_t)SLOT_CAP * 4);
  int* tok_e = (int*)take((size_t)NTOK * 2 * 4);
  float* tok_g = (float*)take((size_t)NTOK * 2 * 4);
  int* slot_of = (int*)take((size_t)NTOK * 2 * 4);
  int* counts = (int*)take(E_ * 4);
  int* cursor = (int*)take(E_ * 4);
  int* offs = (int*)take((E_ + 1) * 4);

  cvt_w13_kernel<<<4096, 256, 0, stream>>>(w1, w3, w13, E_ * F_ * D_ / 4);
  cvt_kernel<<<4096, 256, 0, stream>>>(w2, w2h, E_ * D_ * F_ / 4);
  init_kernel<<<(SLOT_CAP + 255) / 256, 256, 0, stream>>>(slot_token, counts, cursor);
  router_kernel<<<NTOK / 4, 256, 0, stream>>>(x, rw, rbc, x16, tok_e, tok_g, counts);
  scan_kernel<<<1, 64, 0, stream>>>(counts, offs);
  scatter_kernel<<<(NTOK * 2 + 255) / 256, 256, 0, stream>>>(tok_e, offs, cursor, slot_token, slot_of);
  // gemm1: M<=18432 x Nvirt=8192 x K=1024 -> grid 8*18*32
  moe_gemm_kernel<0, 1024, 32, 18, 8192><<<4608, 512, 0, stream>>>(
      x16, w13, slot_token, offs, (void*)hbuf);
  // gemm2: M<=18432 x N=1024 x K=4096 -> grid 8*18*4
  moe_gemm_kernel<1, 4096, 4, 18, 1024><<<576, 512, 0, stream>>>(
      hbuf, w2h, slot_token, offs, (void*)ybuf);
  combine_kernel<<<NTOK, 256, 0, stream>>>(ybuf, slot_of, tok_g, out);
}

// Round 5
// 897.537 us; speedup vs baseline: 1.1014x; 1.0140x over previous
//
#include <hip/hip_runtime.h>
#include <hip/hip_fp16.h>

// MoE top-2 SwiGLU, MI355X. Sparse grouped-GEMM, 256-aligned expert segments.
// gemm1: 256x256 tile (LDS-BW-optimal), 8 waves, 16x16x32 f16 MFMA, proven
//   0-conflict XOR swizzle via pre-swizzled global source, 3 LDS buffers,
//   distance-2 prefetch, one barrier + counted vmcnt per K-step.
//   w1/w3 interleaved at 16-col granularity -> silu*mul -> h fp16.
// gemm2: 128x256 (R4-proven), nb-fastest XCD ordering so the 4 N-blocks of one
//   row-block share the A-panel in their XCD L2 (A=151MB is the big operand).
// combine: out = g0*y0 + g1*y1.

#define NTOK 8192
#define D_ 1024
#define F_ 4096
#define E_ 8
#define SLOT_CAP 18432  // 2*8192 + 8*256

using half8 = __attribute__((ext_vector_type(8))) _Float16;
using half4 = __attribute__((ext_vector_type(4))) _Float16;
using f32x4 = __attribute__((ext_vector_type(4))) float;

__device__ __forceinline__ void gload16(const void* g, void* l) {
  __builtin_amdgcn_global_load_lds((const __attribute__((address_space(1))) void*)g,
                                   (__attribute__((address_space(3))) void*)l, 16, 0, 0);
}

// ---------------- fp32 -> fp16 convert ----------------
__global__ __launch_bounds__(256) void cvt_kernel(const float* __restrict__ src,
                                                  _Float16* __restrict__ dst, int n4) {
  int i = blockIdx.x * 256 + threadIdx.x;
  int stride = gridDim.x * 256;
  for (; i < n4; i += stride) {
    float4 v = ((const float4*)src)[i];
    half4 h;
    h.x = (_Float16)v.x; h.y = (_Float16)v.y; h.z = (_Float16)v.z; h.w = (_Float16)v.w;
    ((half4*)dst)[i] = h;
  }
}

// w1,w3 -> interleaved virtual rows w13[e][8192][1024]:
// vrow = ((f>>4)<<5) | (sel<<4) | (f&15); sel 0=w1(gate), 1=w3(up).
__global__ __launch_bounds__(256) void cvt_w13_kernel(const float* __restrict__ w1,
                                                      const float* __restrict__ w3,
                                                      _Float16* __restrict__ w13, int n4) {
  int i = blockIdx.x * 256 + threadIdx.x;
  int stride = gridDim.x * 256;
  for (; i < n4; i += stride) {
    int d4 = i & 255;   // D/4 = 256
    int row = i >> 8;   // e*4096 + f
    int e = row >> 12, f = row & 4095;
    size_t vbase = ((size_t)e << 13) | ((size_t)(f >> 4) << 5) | (size_t)(f & 15);
    float4 v1 = ((const float4*)w1)[i];
    float4 v3 = ((const float4*)w3)[i];
    half4 h1, h3;
    h1.x = (_Float16)v1.x; h1.y = (_Float16)v1.y; h1.z = (_Float16)v1.z; h1.w = (_Float16)v1.w;
    h3.x = (_Float16)v3.x; h3.y = (_Float16)v3.y; h3.z = (_Float16)v3.z; h3.w = (_Float16)v3.w;
    ((half4*)w13)[vbase * 256 + d4] = h1;
    ((half4*)w13)[(vbase + 16) * 256 + d4] = h3;
  }
}

// ---------------- router (+ fused x fp32->fp16) ----------------
__global__ __launch_bounds__(256) void router_kernel(
    const float* __restrict__ x, const float* __restrict__ rw, const float* __restrict__ rbias,
    _Float16* __restrict__ x16, int* __restrict__ tok_e, float* __restrict__ tok_g,
    int* __restrict__ counts) {
  int wv = threadIdx.x >> 6, lane = threadIdx.x & 63;
  int t = blockIdx.x * 4 + wv;
  const float4* xr = (const float4*)(x + (size_t)t * D_);
  float acc[E_];
#pragma unroll
  for (int e = 0; e < E_; ++e) acc[e] = 0.f;
  for (int i = lane; i < D_ / 4; i += 64) {
    float4 xv = xr[i];
    half4 hx;
    hx.x = (_Float16)xv.x; hx.y = (_Float16)xv.y; hx.z = (_Float16)xv.z; hx.w = (_Float16)xv.w;
    ((half4*)(x16 + (size_t)t * D_))[i] = hx;
#pragma unroll
    for (int e = 0; e < E_; ++e) {
      float4 wv4 = ((const float4*)(rw + (size_t)e * D_))[i];
      acc[e] += xv.x * wv4.x + xv.y * wv4.y + xv.z * wv4.z + xv.w * wv4.w;
    }
  }
#pragma unroll
  for (int e = 0; e < E_; ++e) {
#pragma unroll
    for (int off = 32; off > 0; off >>= 1) acc[e] += __shfl_down(acc[e], off);
  }
  if (lane == 0) {
    float p[E_], mx = -1e30f;
#pragma unroll
    for (int e = 0; e < E_; ++e) { p[e] = acc[e] + rbias[e]; mx = fmaxf(mx, p[e]); }
#pragma unroll
    for (int e = 0; e < E_; ++e) p[e] = expf(p[e] - mx);
    int i0 = 0;
#pragma unroll
    for (int e = 1; e < E_; ++e) if (p[e] > p[i0]) i0 = e;
    int i1 = (i0 == 0) ? 1 : 0;
#pragma unroll
    for (int e = 0; e < E_; ++e) if (e != i0 && p[e] > p[i1]) i1 = e;
    float s = p[i0] + p[i1];
    tok_e[t * 2] = i0; tok_e[t * 2 + 1] = i1;
    tok_g[t * 2] = p[i0] / s; tok_g[t * 2 + 1] = p[i1] / s;
    atomicAdd(&counts[i0], 1); atomicAdd(&counts[i1], 1);
  }
}

__global__ void init_kernel(int* slot_token, int* counts, int* cursor) {
  int i = blockIdx.x * 256 + threadIdx.x;
  if (blockIdx.x == 0 && threadIdx.x < E_) { counts[threadIdx.x] = 0; cursor[threadIdx.x] = 0; }
  if (i < SLOT_CAP) slot_token[i] = 0;  // padding -> token 0 (never combined)
}

__global__ void scan_kernel(const int* __restrict__ counts, int* __restrict__ offs) {
  if (threadIdx.x == 0) {
    int o = 0;
    for (int e = 0; e < E_; ++e) { offs[e] = o; o += ((counts[e] + 255) / 256) * 256; }
    offs[E_] = o;
  }
}

__global__ void scatter_kernel(const int* __restrict__ tok_e, const int* __restrict__ offs,
                               int* __restrict__ cursor, int* __restrict__ slot_token,
                               int* __restrict__ slot_of) {
  int i = blockIdx.x * 256 + threadIdx.x;
  if (i >= NTOK * 2) return;
  int e = tok_e[i];
  int pos = offs[e] + atomicAdd(&cursor[e], 1);
  slot_token[pos] = i >> 1;
  slot_of[i] = pos;
}

// ---------------- pipelined grouped GEMM (16x16x32 f16, BN=256) ----------------
// 8 waves (2 wr x 4 wc), per-wave (BM/2) x 64 output. 3 LDS buffers, distance-2.
// MODE 0: gather-A via slot_token, swiglu epilogue -> fp16 h.  MODE 1: direct-A -> fp32.
// ORD 0: rb-fastest within 8-band per XCD (share B panel).  ORD 1: nb-fastest (share A panel).
// MINW: min waves/EU for launch_bounds.
template <int BM, int MODE, int ORD, int MINW, int KD, int NBN, int RPX, int BEROWS>
__global__ __launch_bounds__(512, MINW) void moe_gemm_kernel(
    const _Float16* __restrict__ Amat, const _Float16* __restrict__ Bmat,
    const int* __restrict__ slot_token, const int* __restrict__ offs,
    void* __restrict__ outp) {
  constexpr int MROW = BM / 32;          // 16-row m-frags per wave
  constexpr int AINS = BM / 128;         // A stage instrs (512 thr x 16B = 128 rows each)
  constexpr int S = AINS + 2;            // stage instrs per tile
  constexpr int AH = BM * 32;            // A halves per buffer
  constexpr int BUFH = (BM + 256) * 32;
  constexpr int NT = KD / 32;
  __shared__ _Float16 lds[3 * BUFH];

  int id = blockIdx.x;
  int xcd = id & 7, idx = id >> 3;  // grid = 8 * RPX * NBN
  int rb, nb;
  if constexpr (ORD == 0) {
    int band = idx / (8 * NBN);
    int i2 = idx - band * (8 * NBN);
    int rib = (RPX - band * 8) < 8 ? (RPX - band * 8) : 8;
    nb = i2 / rib;
    rb = xcd * RPX + band * 8 + (i2 - nb * rib);
  } else {
    nb = idx % NBN;
    rb = xcd * RPX + idx / NBN;
  }
  int row0 = rb * BM;
  if (row0 >= offs[E_]) return;
  int e = 0;
#pragma unroll
  for (int i = 1; i < E_; ++i) if (row0 >= offs[i]) e = i;

  int t = threadIdx.x, l = t & 63, w = t >> 6;
  int wr = w >> 2, wc = w & 3;
  int srow = t >> 2;                           // 0..127 staging row
  int gsrc8 = ((l & 3) ^ ((l >> 3) & 3)) * 8;  // pre-swizzled source k-granule

  const _Float16* aSrc[AINS];
  if constexpr (MODE == 0) {
#pragma unroll
    for (int ins = 0; ins < AINS; ++ins) {
      int tk = slot_token[row0 + srow + ins * 128];
      aSrc[ins] = Amat + (size_t)tk * KD + gsrc8;
    }
  } else {
#pragma unroll
    for (int ins = 0; ins < AINS; ++ins)
      aSrc[ins] = Amat + (size_t)(row0 + srow + ins * 128) * KD + gsrc8;
  }
  const _Float16* bSrc0 = Bmat + ((size_t)e * BEROWS + (size_t)nb * 256 + srow) * KD + gsrc8;
  const _Float16* bSrc1 = bSrc0 + (size_t)128 * KD;

  auto stage = [&](int bi, int tt) {
#pragma unroll
    for (int ins = 0; ins < AINS; ++ins)
      gload16(aSrc[ins] + tt * 32, &lds[bi * BUFH + ins * 4096 + w * 512]);
    gload16(bSrc0 + tt * 32, &lds[bi * BUFH + AH + w * 512]);
    gload16(bSrc1 + tt * 32, &lds[bi * BUFH + AH + 4096 + w * 512]);
  };

  // proven 0-conflict read pattern: 16-row frags, granule kg = l>>4
  int fr = l & 15, kg = l >> 4;
  int swz8 = (kg ^ ((fr >> 1) & 3)) * 8;
  const int rA = (wr * (BM / 2) + fr) * 32 + swz8;
  const int rB = AH + (wc * 64 + fr) * 32 + swz8;
  auto ldA = [&](int bi, int mi) { return *(const half8*)&lds[bi * BUFH + rA + mi * 512]; };
  auto ldB = [&](int bi, int ni) { return *(const half8*)&lds[bi * BUFH + rB + ni * 512]; };

  f32x4 acc[MROW][4];
#pragma unroll
  for (int m = 0; m < MROW; ++m)
#pragma unroll
    for (int n = 0; n < 4; ++n) acc[m][n] = (f32x4){0.f, 0.f, 0.f, 0.f};

  // prologue: stage tiles 0,1; wait tile 0 (tile 1's S loads stay in flight)
  stage(0, 0); stage(1, 1);
  asm volatile("s_waitcnt vmcnt(%0)" ::"i"(S) : "memory");
  __builtin_amdgcn_s_barrier();
  __builtin_amdgcn_sched_barrier(0);

  int b0 = 0, b1 = 1, b2 = 2;
  for (int j = 0; j < NT; ++j) {
    half8 a[MROW], b[4];
#pragma unroll
    for (int mi = 0; mi < MROW; ++mi) a[mi] = ldA(b0, mi);
#pragma unroll
    for (int ni = 0; ni < 4; ++ni) b[ni] = ldB(b0, ni);
    if (j + 2 < NT) stage(b2, j + 2);
    __builtin_amdgcn_s_setprio(1);
#pragma unroll
    for (int mi = 0; mi < MROW; ++mi)
#pragma unroll
      for (int ni = 0; ni < 4; ++ni)
        acc[mi][ni] = __builtin_amdgcn_mfma_f32_16x16x32_f16(a[mi], b[ni], acc[mi][ni], 0, 0, 0);
    __builtin_amdgcn_s_setprio(0);
    int ahead = NT - 1 - j;
    if (ahead >= 2)      asm volatile("s_waitcnt vmcnt(%0)" ::"i"(S) : "memory");
    else if (ahead == 1) asm volatile("s_waitcnt vmcnt(0)" ::: "memory");
    if (ahead >= 1) {
      __builtin_amdgcn_s_barrier();
      __builtin_amdgcn_sched_barrier(0);
    }
    int tmp = b0; b0 = b1; b1 = b2; b2 = tmp;
  }

  // epilogue. C/D 16x16: col = lane&15, row = (lane>>4)*4 + i  [m89 verified]
  int q4 = kg * 4;
  if constexpr (MODE == 0) {
    _Float16* hb = (_Float16*)outp;
#pragma unroll
    for (int mi = 0; mi < MROW; ++mi) {
      size_t rbase = (size_t)(row0 + wr * (BM / 2) + mi * 16 + q4);
#pragma unroll
      for (int p = 0; p < 2; ++p) {
        int fc = nb * 128 + (wc * 2 + p) * 16 + fr;
#pragma unroll
        for (int i = 0; i < 4; ++i) {
          float gv = acc[mi][2 * p][i];
          float hv = gv / (1.f + __expf(-gv)) * acc[mi][2 * p + 1][i];
          hb[(rbase + i) * (size_t)F_ + fc] = (_Float16)hv;
        }
      }
    }
  } else {
    float* yb = (float*)outp;
#pragma unroll
    for (int mi = 0; mi < MROW; ++mi) {
      size_t rbase = (size_t)(row0 + wr * (BM / 2) + mi * 16 + q4);
#pragma unroll
      for (int ni = 0; ni < 4; ++ni) {
        int col = nb * 256 + wc * 64 + ni * 16 + fr;
#pragma unroll
        for (int i = 0; i < 4; ++i)
          yb[(rbase + i) * (size_t)D_ + col] = acc[mi][ni][i];
      }
    }
  }
}

// ---------------- combine ----------------
__global__ __launch_bounds__(256) void combine_kernel(
    const float* __restrict__ ybuf, const int* __restrict__ slot_of,
    const float* __restrict__ tok_g, float* __restrict__ out) {
  int t = blockIdx.x, i = threadIdx.x;
  int s0 = slot_of[t * 2], s1 = slot_of[t * 2 + 1];
  float g0 = tok_g[t * 2], g1 = tok_g[t * 2 + 1];
  float4 a = ((const float4*)(ybuf + (size_t)s0 * D_))[i];
  float4 b = ((const float4*)(ybuf + (size_t)s1 * D_))[i];
  float4 r;
  r.x = g0 * a.x + g1 * b.x;
  r.y = g0 * a.y + g1 * b.y;
  r.z = g0 * a.z + g1 * b.z;
  r.w = g0 * a.w + g1 * b.w;
  ((float4*)(out + (size_t)t * D_))[i] = r;
}

extern "C" void kernel_launch(void* const* d_in, const int* in_sizes, int n_in,
                              void* d_out, int out_size, void* d_ws, size_t ws_size,
                              hipStream_t stream) {
  const float* x  = (const float*)d_in[0];
  const float* rw = (const float*)d_in[1];
  const float* rbc = (const float*)d_in[2];
  const float* w1 = (const float*)d_in[3];
  const float* w2 = (const float*)d_in[4];  // dict order: w2 before w3
  const float* w3 = (const float*)d_in[5];
  float* out = (float*)d_out;

  char* ws = (char*)d_ws;
  size_t off = 0;
  auto take = [&](size_t bytes) {
    char* p = ws + off;
    off = (off + bytes + 255) & ~(size_t)255;
    return p;
  };
  _Float16* x16 = (_Float16*)take((size_t)NTOK * D_ * 2);
  _Float16* w13 = (_Float16*)take((size_t)E_ * 2 * F_ * D_ * 2);  // 128 MB
  _Float16* w2h = (_Float16*)take((size_t)E_ * D_ * F_ * 2);      // 64 MB
  _Float16* hbuf = (_Float16*)take((size_t)SLOT_CAP * F_ * 2);    // 151 MB
  float* ybuf = (float*)take((size_t)SLOT_CAP * D_ * 4);          // 75.5 MB
  int* slot_token = (int*)take((size_t)SLOT_CAP * 4);
  int* tok_e = (int*)take((size_t)NTOK * 2 * 4);
  float* tok_g = (float*)take((size_t)NTOK * 2 * 4);
  int* slot_of = (int*)take((size_t)NTOK * 2 * 4);
  int* counts = (int*)take(E_ * 4);
  int* cursor = (int*)take(E_ * 4);
  int* offs = (int*)take((E_ + 1) * 4);

  cvt_w13_kernel<<<4096, 256, 0, stream>>>(w1, w3, w13, E_ * F_ * D_ / 4);
  cvt_kernel<<<4096, 256, 0, stream>>>(w2, w2h, E_ * D_ * F_ / 4);
  init_kernel<<<(SLOT_CAP + 255) / 256, 256, 0, stream>>>(slot_token, counts, cursor);
  router_kernel<<<NTOK / 4, 256, 0, stream>>>(x, rw, rbc, x16, tok_e, tok_g, counts);
  scan_kernel<<<1, 64, 0, stream>>>(counts, offs);
  scatter_kernel<<<(NTOK * 2 + 255) / 256, 256, 0, stream>>>(tok_e, offs, cursor, slot_token, slot_of);
  // gemm1: 256x256 tile, M<=18432 x Nvirt=8192 x K=1024 -> grid 8*9*32, 1 block/CU
  moe_gemm_kernel<256, 0, 0, 2, 1024, 32, 9, 8192><<<2304, 512, 0, stream>>>(
      x16, w13, slot_token, offs, (void*)hbuf);
  // gemm2: 128x256, M<=18432 x N=1024 x K=4096 -> grid 8*18*4, A-panel-sharing order
  moe_gemm_kernel<128, 1, 1, 4, 4096, 4, 18, 1024><<<576, 512, 0, stream>>>(
      hbuf, w2h, slot_token, offs, (void*)ybuf);
  combine_kernel<<<NTOK, 256, 0, stream>>>(ybuf, slot_of, tok_g, out);
}